// Round 4
// baseline (983.249 us; speedup 1.0000x reference)
//
#include <hip/hip_runtime.h>

typedef unsigned short u16;
typedef __attribute__((ext_vector_type(8))) short bf16x8;
typedef __attribute__((ext_vector_type(4))) float f32x4;
typedef __attribute__((ext_vector_type(4))) unsigned short u16x4;

#define MFMA16(a, b, c) __builtin_amdgcn_mfma_f32_16x16x32_bf16((a), (b), (c), 0, 0, 0)

__device__ __forceinline__ u16 f2bf(float f) {
  union { float f; unsigned int i; } v; v.f = f;
  return (u16)((v.i + 0x7FFFu + ((v.i >> 16) & 1u)) >> 16);
}

// ---------------- GEMM: A[M][K] @ B[K][N] ----------------
// QKV=1: A fp32, epilogue scatters bf16 to Q/K/V^T.
// QKV=0: A bf16, epilogue writes fp32 C + fp32 bias.
template <int QKV>
__global__ __launch_bounds__(256) void k_gemm(
    const void* __restrict__ Ap, const float* __restrict__ B,
    const float* __restrict__ bias, float* __restrict__ Cf,
    u16* __restrict__ Qb, u16* __restrict__ Kb, u16* __restrict__ VTb,
    int M, int N, int K) {
  __shared__ __attribute__((aligned(16))) u16 As[128 * 32];  // [row][k]
  __shared__ __attribute__((aligned(16))) u16 Bs[128 * 32];  // [col][k]
  const int bn = blockIdx.x, bm = blockIdx.y;
  const int t = threadIdx.x, lane = t & 63, w = t >> 6;
  const int wr = w >> 1, wc = w & 1;        // 2x2 wave grid, 64x64 per wave
  const int rh = lane & 15, kg = lane >> 4; // fragment row / k-group

  f32x4 acc[4][4];
#pragma unroll
  for (int mi = 0; mi < 4; ++mi)
#pragma unroll
    for (int ni = 0; ni < 4; ++ni) acc[mi][ni] = (f32x4)0.0f;

  for (int k0 = 0; k0 < K; k0 += 32) {
    // --- A tile: rows bm*128+[0,128), k=[k0,k0+32) ---
#pragma unroll
    for (int i = 0; i < 2; ++i) {
      int c = t + 256 * i;
      int r = c >> 2, c8 = (c & 3) << 3;
      if (QKV) {  // fp32 A -> convert
        const float* s = (const float*)Ap + (size_t)(bm * 128 + r) * K + k0 + c8;
        float4 a = *(const float4*)s;
        float4 b4 = *(const float4*)(s + 4);
        union { u16 e[8]; int4 v; } u;
        u.e[0] = f2bf(a.x); u.e[1] = f2bf(a.y); u.e[2] = f2bf(a.z); u.e[3] = f2bf(a.w);
        u.e[4] = f2bf(b4.x); u.e[5] = f2bf(b4.y); u.e[6] = f2bf(b4.z); u.e[7] = f2bf(b4.w);
        *(int4*)(&As[r * 32 + c8]) = u.v;
      } else {    // bf16 A -> copy
        const u16* s = (const u16*)Ap + (size_t)(bm * 128 + r) * K + k0 + c8;
        *(int4*)(&As[r * 32 + c8]) = *(const int4*)s;
      }
    }
    // --- B tile: fp32 [K][N], transposing store Bs[col][k] ---
#pragma unroll
    for (int p = 0; p < 4; ++p) {
      int kl = p * 8 + (t >> 5);   // 0..31
      int c4 = (t & 31) << 2;      // 0..124
      const float* s = B + (size_t)(k0 + kl) * N + bn * 128 + c4;
      float4 v = *(const float4*)s;
      Bs[(c4 + 0) * 32 + kl] = f2bf(v.x);
      Bs[(c4 + 1) * 32 + kl] = f2bf(v.y);
      Bs[(c4 + 2) * 32 + kl] = f2bf(v.z);
      Bs[(c4 + 3) * 32 + kl] = f2bf(v.w);
    }
    __syncthreads();
    bf16x8 af[4], bfr[4];
#pragma unroll
    for (int mi = 0; mi < 4; ++mi)
      af[mi] = *(const bf16x8*)(&As[(wr * 64 + mi * 16 + rh) * 32 + kg * 8]);
#pragma unroll
    for (int ni = 0; ni < 4; ++ni)
      bfr[ni] = *(const bf16x8*)(&Bs[(wc * 64 + ni * 16 + rh) * 32 + kg * 8]);
#pragma unroll
    for (int mi = 0; mi < 4; ++mi)
#pragma unroll
      for (int ni = 0; ni < 4; ++ni)
        acc[mi][ni] = MFMA16(af[mi], bfr[ni], acc[mi][ni]);
    __syncthreads();
  }

  if (QKV == 0) {
    // fp32 C with fp32 bias
    const int rbase = bm * 128 + wr * 64;
    const int cbase = bn * 128 + wc * 64;
#pragma unroll
    for (int ni = 0; ni < 4; ++ni) {
      const int col = cbase + ni * 16 + rh;
      const float bv = bias ? bias[col] : 0.0f;
#pragma unroll
      for (int mi = 0; mi < 4; ++mi) {
#pragma unroll
        for (int r = 0; r < 4; ++r) {
          int row = rbase + mi * 16 + kg * 4 + r;
          Cf[(size_t)row * N + col] = acc[mi][ni][r] + bv;
        }
      }
    }
  } else {
    // qkv scatter: row = b*2048+t, col in [0,3072): role=col/1024, h=(col%1024)/64, d=col%64
    const int rowbase = bm * 128 + wr * 64;
    const int b = rowbase >> 11;
    const int tb = rowbase & 2047;
    const int cbase = bn * 128 + wc * 64;  // 64-aligned -> role/h uniform per wave
    const int role = cbase >> 10;
    const int h = (cbase & 1023) >> 6;
    const int bh = b * 16 + h;
#pragma unroll
    for (int ni = 0; ni < 4; ++ni) {
      const int d = ni * 16 + rh;
#pragma unroll
      for (int mi = 0; mi < 4; ++mi) {
        const int tt = tb + mi * 16 + kg * 4;
        if (role == 2) {
          u16x4 pk;
#pragma unroll
          for (int r = 0; r < 4; ++r) pk[r] = f2bf(acc[mi][ni][r]);
          *(u16x4*)(&VTb[((size_t)bh * 64 + d) * 2048 + tt]) = pk;  // V^T[bh][d][t]
        } else {
          u16* dst = (role == 0) ? Qb : Kb;
#pragma unroll
          for (int r = 0; r < 4; ++r)
            dst[((size_t)bh * 2048 + tt + r) * 64 + d] = f2bf(acc[mi][ni][r]);
        }
      }
    }
  }
}

// ---------------- causal flash attention ----------------
// Q,K: [BH][2048][64]; VT: [BH][64][2048]; Y: [B*2048][1024] bf16
__global__ __launch_bounds__(256) void k_attn(const u16* __restrict__ Qb,
                                              const u16* __restrict__ Kb,
                                              const u16* __restrict__ VTb,
                                              u16* __restrict__ Y) {
  __shared__ __attribute__((aligned(16))) u16 Pl[4][16 * 32];
  const int bh = blockIdx.y, qblk = blockIdx.x;
  const int t = threadIdx.x, lane = t & 63, w = t >> 6;
  const int rh = lane & 15, kg = lane >> 4;
  const int q0 = qblk * 64 + w * 16;  // this wave's 16 q-rows
  const u16* Qh = Qb + (size_t)bh * 2048 * 64;
  const u16* Kh = Kb + (size_t)bh * 2048 * 64;
  const u16* Vh = VTb + (size_t)bh * 64 * 2048;

  const bf16x8 qf0 = *(const bf16x8*)(&Qh[(q0 + rh) * 64 + kg * 8]);
  const bf16x8 qf1 = *(const bf16x8*)(&Qh[(q0 + rh) * 64 + 32 + kg * 8]);

  float m[4], s[4];
  f32x4 yacc[4];
#pragma unroll
  for (int r = 0; r < 4; ++r) { m[r] = -1e30f; s[r] = 0.0f; }
#pragma unroll
  for (int dt = 0; dt < 4; ++dt) yacc[dt] = (f32x4)0.0f;

  const int jend = q0 + 16;  // causal: need cols <= q0+15
  for (int j0 = 0; j0 < jend; j0 += 32) {
    f32x4 sa0 = (f32x4)0.0f, sa1 = (f32x4)0.0f;
    {
      bf16x8 kf;
      kf = *(const bf16x8*)(&Kh[(j0 + rh) * 64 + kg * 8]);
      sa0 = MFMA16(qf0, kf, sa0);
      kf = *(const bf16x8*)(&Kh[(j0 + rh) * 64 + 32 + kg * 8]);
      sa0 = MFMA16(qf1, kf, sa0);
      kf = *(const bf16x8*)(&Kh[(j0 + 16 + rh) * 64 + kg * 8]);
      sa1 = MFMA16(qf0, kf, sa1);
      kf = *(const bf16x8*)(&Kh[(j0 + 16 + rh) * 64 + 32 + kg * 8]);
      sa1 = MFMA16(qf1, kf, sa1);
    }
    float sc[4];
#pragma unroll
    for (int r = 0; r < 4; ++r) {
      const int row = q0 + kg * 4 + r;
      float v0 = sa0[r] * 0.125f;  // 1/sqrt(64)
      float v1 = sa1[r] * 0.125f;
      if (j0 + rh > row) v0 = -1e30f;
      if (j0 + 16 + rh > row) v1 = -1e30f;
      float mx = fmaxf(v0, v1);
      mx = fmaxf(mx, __shfl_xor(mx, 1));
      mx = fmaxf(mx, __shfl_xor(mx, 2));
      mx = fmaxf(mx, __shfl_xor(mx, 4));
      mx = fmaxf(mx, __shfl_xor(mx, 8));
      const float mn = fmaxf(m[r], mx);
      sc[r] = __expf(m[r] - mn);
      const float p0 = __expf(v0 - mn);
      const float p1 = __expf(v1 - mn);
      float rs = p0 + p1;
      rs += __shfl_xor(rs, 1);
      rs += __shfl_xor(rs, 2);
      rs += __shfl_xor(rs, 4);
      rs += __shfl_xor(rs, 8);
      s[r] = s[r] * sc[r] + rs;
      m[r] = mn;
      Pl[w][(kg * 4 + r) * 32 + rh] = f2bf(p0);
      Pl[w][(kg * 4 + r) * 32 + 16 + rh] = f2bf(p1);
    }
#pragma unroll
    for (int dt = 0; dt < 4; ++dt) {
#pragma unroll
      for (int r = 0; r < 4; ++r) yacc[dt][r] *= sc[r];
    }
    // per-wave LDS fence: P writes (other lanes) -> P fragment read
    asm volatile("s_waitcnt lgkmcnt(0)" ::: "memory");
    __builtin_amdgcn_sched_barrier(0);  // rule #18: block hoisting past the waitcnt
    const bf16x8 pf = *(const bf16x8*)(&Pl[w][rh * 32 + kg * 8]);
#pragma unroll
    for (int dt = 0; dt < 4; ++dt) {
      bf16x8 vf = *(const bf16x8*)(&Vh[(dt * 16 + rh) * 2048 + j0 + kg * 8]);
      yacc[dt] = MFMA16(pf, vf, yacc[dt]);
    }
  }

  const int b = bh >> 4, h = bh & 15;
#pragma unroll
  for (int dt = 0; dt < 4; ++dt) {
#pragma unroll
    for (int r = 0; r < 4; ++r) {
      const int row = q0 + kg * 4 + r;
      const float inv = 1.0f / s[r];
      Y[((size_t)b * 2048 + row) * 1024 + h * 64 + dt * 16 + rh] = f2bf(yacc[dt][r] * inv);
    }
  }
}

extern "C" void kernel_launch(void* const* d_in, const int* in_sizes, int n_in,
                              void* d_out, int out_size, void* d_ws, size_t ws_size,
                              hipStream_t stream) {
  const float* x      = (const float*)d_in[0];  // [4,2048,1024] fp32
  const float* w_qkv  = (const float*)d_in[1];  // [1024,3072]   fp32
  const float* w_proj = (const float*)d_in[2];  // [1024,1024]   fp32
  const float* b_proj = (const float*)d_in[3];  // [1024]        fp32
  float* out = (float*)d_out;                   // [4,2048,1024] fp32 (reference dtype)

  char* ws = (char*)d_ws;
  u16* Qb  = (u16*)(ws);             // [64][2048][64] bf16 16.78 MB
  u16* Kb  = (u16*)(ws + 16777216);  // [64][2048][64] bf16 16.78 MB
  u16* VTb = (u16*)(ws + 33554432);  // [64][64][2048] bf16 16.78 MB
  u16* Yb  = (u16*)(ws + 50331648);  // [8192][1024]   bf16 16.78 MB (total 64 MiB)

  k_gemm<1><<<dim3(24, 64), 256, 0, stream>>>(x, w_qkv, nullptr, nullptr,
                                              Qb, Kb, VTb, 8192, 3072, 1024);
  k_attn<<<dim3(32, 64), 256, 0, stream>>>(Qb, Kb, VTb, Yb);
  k_gemm<0><<<dim3(8, 64), 256, 0, stream>>>(Yb, w_proj, b_proj, out,
                                             nullptr, nullptr, nullptr, 8192, 1024, 1024);
}

// Round 5
// 321.352 us; speedup vs baseline: 3.0597x; 3.0597x over previous
//
#include <hip/hip_runtime.h>

typedef unsigned short u16;
typedef __attribute__((ext_vector_type(8))) short bf16x8;
typedef __attribute__((ext_vector_type(4))) float f32x4;
typedef __attribute__((ext_vector_type(4))) unsigned short u16x4;

#define MFMA16(a, b, c) __builtin_amdgcn_mfma_f32_16x16x32_bf16((a), (b), (c), 0, 0, 0)

__device__ __forceinline__ u16 f2bf(float f) {
  union { float f; unsigned int i; } v; v.f = f;
  return (u16)((v.i + 0x7FFFu + ((v.i >> 16) & 1u)) >> 16);
}

// ---------------- transpose fp32 -> bf16: dst[C][R] = src[R][C] ----------------
__global__ __launch_bounds__(256) void k_transpose(const float* __restrict__ src,
                                                   u16* __restrict__ dst, int R, int C) {
  __shared__ u16 tile[64][65];
  const int c0 = blockIdx.x * 64, r0 = blockIdx.y * 64;
  const int t = threadIdx.x;
#pragma unroll
  for (int i = 0; i < 16; ++i) {
    int e = i * 256 + t, rr = e >> 6, cc = e & 63;
    tile[rr][cc] = f2bf(src[(size_t)(r0 + rr) * C + c0 + cc]);
  }
  __syncthreads();
#pragma unroll
  for (int i = 0; i < 16; ++i) {
    int e = i * 256 + t, rr = e >> 6, cc = e & 63;
    dst[(size_t)(c0 + rr) * R + r0 + cc] = tile[cc][rr];
  }
}

// ---------------- GEMM: A[M][K] @ Bt[N][K]^T ----------------
// QKV=1: A fp32, epilogue scatters bf16 to Q/K/V^T.
// QKV=0: A bf16, epilogue writes fp32 C + fp32 bias.
template <int QKV>
__global__ __launch_bounds__(256) void k_gemm(
    const void* __restrict__ Ap, const u16* __restrict__ Bt,
    const float* __restrict__ bias, float* __restrict__ Cf,
    u16* __restrict__ Qb, u16* __restrict__ Kb, u16* __restrict__ VTb,
    int M, int N, int K) {
  __shared__ __attribute__((aligned(16))) u16 As[128 * 32];  // [row][k]
  __shared__ __attribute__((aligned(16))) u16 Bs[128 * 32];  // [col][k]
  const int bn = blockIdx.x, bm = blockIdx.y;
  const int t = threadIdx.x, lane = t & 63, w = t >> 6;
  const int wr = w >> 1, wc = w & 1;        // 2x2 wave grid, 64x64 per wave
  const int rh = lane & 15, kg = lane >> 4; // fragment row / k-group

  f32x4 acc[4][4];
#pragma unroll
  for (int mi = 0; mi < 4; ++mi)
#pragma unroll
    for (int ni = 0; ni < 4; ++ni) acc[mi][ni] = (f32x4)0.0f;

  for (int k0 = 0; k0 < K; k0 += 32) {
#pragma unroll
    for (int i = 0; i < 2; ++i) {
      int c = t + 256 * i;
      int r = c >> 2, c8 = (c & 3) << 3;
      // A tile
      if (QKV) {  // fp32 -> bf16
        const float* s = (const float*)Ap + (size_t)(bm * 128 + r) * K + k0 + c8;
        float4 a = *(const float4*)s;
        float4 b4 = *(const float4*)(s + 4);
        union { u16 e[8]; int4 v; } u;
        u.e[0] = f2bf(a.x); u.e[1] = f2bf(a.y); u.e[2] = f2bf(a.z); u.e[3] = f2bf(a.w);
        u.e[4] = f2bf(b4.x); u.e[5] = f2bf(b4.y); u.e[6] = f2bf(b4.z); u.e[7] = f2bf(b4.w);
        *(int4*)(&As[r * 32 + c8]) = u.v;
      } else {    // bf16 copy
        const u16* s = (const u16*)Ap + (size_t)(bm * 128 + r) * K + k0 + c8;
        *(int4*)(&As[r * 32 + c8]) = *(const int4*)s;
      }
      // B tile: bf16 [N][K] -> contiguous 16B copy (conflict-free)
      const u16* sb = Bt + (size_t)(bn * 128 + r) * K + k0 + c8;
      *(int4*)(&Bs[r * 32 + c8]) = *(const int4*)sb;
    }
    __syncthreads();
    bf16x8 af[4], bfr[4];
#pragma unroll
    for (int mi = 0; mi < 4; ++mi)
      af[mi] = *(const bf16x8*)(&As[(wr * 64 + mi * 16 + rh) * 32 + kg * 8]);
#pragma unroll
    for (int ni = 0; ni < 4; ++ni)
      bfr[ni] = *(const bf16x8*)(&Bs[(wc * 64 + ni * 16 + rh) * 32 + kg * 8]);
#pragma unroll
    for (int mi = 0; mi < 4; ++mi)
#pragma unroll
      for (int ni = 0; ni < 4; ++ni)
        acc[mi][ni] = MFMA16(af[mi], bfr[ni], acc[mi][ni]);
    __syncthreads();
  }

  if (QKV == 0) {
    const int rbase = bm * 128 + wr * 64;
    const int cbase = bn * 128 + wc * 64;
#pragma unroll
    for (int ni = 0; ni < 4; ++ni) {
      const int col = cbase + ni * 16 + rh;
      const float bv = bias ? bias[col] : 0.0f;
#pragma unroll
      for (int mi = 0; mi < 4; ++mi) {
#pragma unroll
        for (int r = 0; r < 4; ++r) {
          int row = rbase + mi * 16 + kg * 4 + r;
          Cf[(size_t)row * N + col] = acc[mi][ni][r] + bv;
        }
      }
    }
  } else {
    // qkv scatter: row = b*2048+t, col in [0,3072): role=col/1024, h=(col%1024)/64, d=col%64
    const int rowbase = bm * 128 + wr * 64;
    const int b = rowbase >> 11;
    const int tb = rowbase & 2047;
    const int cbase = bn * 128 + wc * 64;  // 64-aligned -> role/h uniform per wave
    const int role = cbase >> 10;
    const int h = (cbase & 1023) >> 6;
    const int bh = b * 16 + h;
#pragma unroll
    for (int ni = 0; ni < 4; ++ni) {
      const int d = ni * 16 + rh;
#pragma unroll
      for (int mi = 0; mi < 4; ++mi) {
        const int tt = tb + mi * 16 + kg * 4;
        if (role == 2) {
          u16x4 pk;
#pragma unroll
          for (int r = 0; r < 4; ++r) pk[r] = f2bf(acc[mi][ni][r]);
          *(u16x4*)(&VTb[((size_t)bh * 64 + d) * 2048 + tt]) = pk;  // V^T[bh][d][t]
        } else {
          u16* dst = (role == 0) ? Qb : Kb;
#pragma unroll
          for (int r = 0; r < 4; ++r)
            dst[((size_t)bh * 2048 + tt + r) * 64 + d] = f2bf(acc[mi][ni][r]);
        }
      }
    }
  }
}

// ---------------- causal flash attention, 32 q-rows/wave, paired q-tiles ----------------
// Q,K: [BH][2048][64]; VT: [BH][64][2048]; Y: [B*2048][1024] bf16
// Grid (16, 64), block 128 (2 waves). Block processes q-tiles {pair, 31-pair} (64 rows each):
// equal work per block -> no causal tail imbalance.
__global__ __launch_bounds__(128) void k_attn(const u16* __restrict__ Qb,
                                              const u16* __restrict__ Kb,
                                              const u16* __restrict__ VTb,
                                              u16* __restrict__ Y) {
  __shared__ __attribute__((aligned(16))) u16 Pl[2][32 * 32];
  const int bh = blockIdx.y, pair = blockIdx.x;
  const int t = threadIdx.x, lane = t & 63, w = t >> 6;
  const int rh = lane & 15, kg = lane >> 4;
  const u16* Qh = Qb + (size_t)bh * 2048 * 64;
  const u16* Kh = Kb + (size_t)bh * 2048 * 64;
  const u16* Vh = VTb + (size_t)bh * 64 * 2048;
  const int b = bh >> 4, h = bh & 15;

  for (int seg = 0; seg < 2; ++seg) {
    const int qblk = seg ? (31 - pair) : pair;
    const int q0 = qblk * 64 + w * 32;  // this wave's 32 q-rows

    bf16x8 qf[2][2];
#pragma unroll
    for (int rb = 0; rb < 2; ++rb) {
      qf[rb][0] = *(const bf16x8*)(&Qh[(q0 + rb * 16 + rh) * 64 + kg * 8]);
      qf[rb][1] = *(const bf16x8*)(&Qh[(q0 + rb * 16 + rh) * 64 + 32 + kg * 8]);
    }

    float m[2][4], s[2][4];
    f32x4 yacc[2][4];
#pragma unroll
    for (int rb = 0; rb < 2; ++rb) {
#pragma unroll
      for (int r = 0; r < 4; ++r) { m[rb][r] = -1e30f; s[rb][r] = 0.0f; }
#pragma unroll
      for (int dt = 0; dt < 4; ++dt) yacc[rb][dt] = (f32x4)0.0f;
    }

    const int jend = q0 + 32;
    for (int j0 = 0; j0 < jend; j0 += 32) {
      // K fragments (shared across both row-blocks)
      const bf16x8 kf0a = *(const bf16x8*)(&Kh[(j0 + rh) * 64 + kg * 8]);
      const bf16x8 kf0b = *(const bf16x8*)(&Kh[(j0 + rh) * 64 + 32 + kg * 8]);
      const bf16x8 kf1a = *(const bf16x8*)(&Kh[(j0 + 16 + rh) * 64 + kg * 8]);
      const bf16x8 kf1b = *(const bf16x8*)(&Kh[(j0 + 16 + rh) * 64 + 32 + kg * 8]);

      f32x4 sa[2][2];
#pragma unroll
      for (int rb = 0; rb < 2; ++rb) {
        sa[rb][0] = MFMA16(qf[rb][0], kf0a, (f32x4)0.0f);
        sa[rb][0] = MFMA16(qf[rb][1], kf0b, sa[rb][0]);
        sa[rb][1] = MFMA16(qf[rb][0], kf1a, (f32x4)0.0f);
        sa[rb][1] = MFMA16(qf[rb][1], kf1b, sa[rb][1]);
      }

#pragma unroll
      for (int rb = 0; rb < 2; ++rb) {
        float sc[4];
#pragma unroll
        for (int r = 0; r < 4; ++r) {
          const int row = q0 + rb * 16 + kg * 4 + r;
          float v0 = sa[rb][0][r] * 0.125f;  // 1/sqrt(64)
          float v1 = sa[rb][1][r] * 0.125f;
          if (j0 + rh > row) v0 = -1e30f;
          if (j0 + 16 + rh > row) v1 = -1e30f;
          float mx = fmaxf(v0, v1);
          mx = fmaxf(mx, __shfl_xor(mx, 1));
          mx = fmaxf(mx, __shfl_xor(mx, 2));
          mx = fmaxf(mx, __shfl_xor(mx, 4));
          mx = fmaxf(mx, __shfl_xor(mx, 8));
          const float mn = fmaxf(m[rb][r], mx);
          sc[r] = __expf(m[rb][r] - mn);
          const float p0 = __expf(v0 - mn);
          const float p1 = __expf(v1 - mn);
          float rs = p0 + p1;
          rs += __shfl_xor(rs, 1);
          rs += __shfl_xor(rs, 2);
          rs += __shfl_xor(rs, 4);
          rs += __shfl_xor(rs, 8);
          s[rb][r] = s[rb][r] * sc[r] + rs;
          m[rb][r] = mn;
          Pl[w][(rb * 16 + kg * 4 + r) * 32 + rh] = f2bf(p0);
          Pl[w][(rb * 16 + kg * 4 + r) * 32 + 16 + rh] = f2bf(p1);
        }
#pragma unroll
        for (int dt = 0; dt < 4; ++dt)
#pragma unroll
          for (int r = 0; r < 4; ++r) yacc[rb][dt][r] *= sc[r];
      }

      // per-wave LDS fence: P writes -> P fragment reads
      asm volatile("s_waitcnt lgkmcnt(0)" ::: "memory");
      __builtin_amdgcn_sched_barrier(0);
      bf16x8 pf[2];
#pragma unroll
      for (int rb = 0; rb < 2; ++rb)
        pf[rb] = *(const bf16x8*)(&Pl[w][(rb * 16 + rh) * 32 + kg * 8]);
#pragma unroll
      for (int dt = 0; dt < 4; ++dt) {
        const bf16x8 vf = *(const bf16x8*)(&Vh[(dt * 16 + rh) * 2048 + j0 + kg * 8]);
#pragma unroll
        for (int rb = 0; rb < 2; ++rb)
          yacc[rb][dt] = MFMA16(pf[rb], vf, yacc[rb][dt]);
      }
    }

#pragma unroll
    for (int rb = 0; rb < 2; ++rb)
#pragma unroll
      for (int dt = 0; dt < 4; ++dt)
#pragma unroll
        for (int r = 0; r < 4; ++r) {
          const int row = q0 + rb * 16 + kg * 4 + r;
          const float inv = 1.0f / s[rb][r];
          Y[((size_t)b * 2048 + row) * 1024 + h * 64 + dt * 16 + rh] = f2bf(yacc[rb][dt][r] * inv);
        }
  }
}

extern "C" void kernel_launch(void* const* d_in, const int* in_sizes, int n_in,
                              void* d_out, int out_size, void* d_ws, size_t ws_size,
                              hipStream_t stream) {
  const float* x      = (const float*)d_in[0];  // [4,2048,1024] fp32
  const float* w_qkv  = (const float*)d_in[1];  // [1024,3072]   fp32
  const float* w_proj = (const float*)d_in[2];  // [1024,1024]   fp32
  const float* b_proj = (const float*)d_in[3];  // [1024]        fp32
  float* out = (float*)d_out;                   // [4,2048,1024] fp32

  char* ws = (char*)d_ws;
  u16* wqkvT  = (u16*)(ws);             // [3072][1024] bf16  6.29 MB
  u16* wprojT = (u16*)(ws + 6291456);   // [1024][1024] bf16  2.10 MB
  u16* Qb     = (u16*)(ws + 8388608);   // [64][2048][64]    16.78 MB
  u16* Kb     = (u16*)(ws + 25165824);  // [64][2048][64]    16.78 MB
  u16* VTb    = (u16*)(ws + 41943040);  // [64][64][2048]    16.78 MB
  u16* Yb     = (u16*)(ws + 58720256);  // [8192][1024]      16.78 MB (total 75.5 MB)

  k_transpose<<<dim3(48, 16), 256, 0, stream>>>(w_qkv, wqkvT, 1024, 3072);
  k_transpose<<<dim3(16, 16), 256, 0, stream>>>(w_proj, wprojT, 1024, 1024);
  k_gemm<1><<<dim3(24, 64), 256, 0, stream>>>(x, wqkvT, nullptr, nullptr,
                                              Qb, Kb, VTb, 8192, 3072, 1024);
  k_attn<<<dim3(16, 64), 128, 0, stream>>>(Qb, Kb, VTb, Yb);
  k_gemm<0><<<dim3(8, 64), 256, 0, stream>>>(Yb, wprojT, b_proj, out,
                                             nullptr, nullptr, nullptr, 8192, 1024, 1024);
}